// Round 9
// baseline (460.407 us; speedup 1.0000x reference)
//
#include <hip/hip_runtime.h>
#include <math.h>

#define NN 26000
#define NE 208000
#define SCAN_CH 26        // ceil(NN/1024), compile-time
#define CNT_BLOCKS 813    // ceil(NE/256)

typedef __attribute__((ext_vector_type(8))) short bf16x8;
typedef __attribute__((ext_vector_type(4))) float f32x4;
typedef __attribute__((ext_vector_type(2))) float f32x2;
typedef unsigned char u8;

__device__ __forceinline__ float bf2f(ushort u){
  union { unsigned int i; float f; } w; w.i = ((unsigned int)u) << 16; return w.f;
}
__device__ __forceinline__ ushort f2bf(float f){
  union { float f; unsigned int i; } w; w.f = f;
  unsigned int u = w.i + 0x7fffu + ((w.i >> 16) & 1u);  // RNE
  return (ushort)(u >> 16);
}

// ---------------- fused count + weight-prep ----------------
// blocks [0, CNT_BLOCKS): histogram of dst. blocks [CNT_BLOCKS, +1536): weight cvt.
// wbuf layout (ushort): [0) wqT[512][128] | [65536) wkT | [131072) wvT |
// [196608) wcT(wskip+skip_w) | [262144) lin1T[128][512] | [327680) l2rT |
// [344064) l2nT | [360448) l3rT | [376832) l3nT
__global__ void cp_k(const int* __restrict__ dst, int* __restrict__ cnt,
                     const float* __restrict__ wq, const float* __restrict__ wk,
                     const float* __restrict__ wv, const float* __restrict__ wskip,
                     const float* __restrict__ skw, const float* __restrict__ lin1w,
                     const float* __restrict__ l2r, const float* __restrict__ l2n,
                     const float* __restrict__ l3r, const float* __restrict__ l3n,
                     ushort* __restrict__ wbuf){
  if (blockIdx.x < CNT_BLOCKS){
    int e = blockIdx.x*256 + threadIdx.x;
    if (e < NE) atomicAdd(&cnt[dst[e]], 1);
    return;
  }
  int idx = (blockIdx.x - CNT_BLOCKS)*256 + threadIdx.x;
  if (idx >= 393216) return;
  float v;
  if (idx < 262144){
    int seg = idx >> 16;
    int local = idx & 65535;
    int n = local >> 7, kk = local & 127;
    const float* w = (seg == 0) ? wq : (seg == 1) ? wk : (seg == 2) ? wv : wskip;
    v = w[kk*512 + n];
    if (seg == 3) v += skw[kk*512 + n];
  } else if (idx < 327680){
    int local = idx - 262144;
    int n = local >> 9, kk = local & 511;
    v = lin1w[kk*128 + n];
  } else {
    int rem = idx - 327680;
    int seg = rem >> 14;
    int local = rem & 16383;
    int n = local >> 7, kk = local & 127;
    const float* w = (seg == 0) ? l2r : (seg == 1) ? l2n : (seg == 2) ? l3r : l3n;
    v = w[kk*128 + n];
  }
  wbuf[idx] = f2bf(v);
}

// ---------------- scan (single block, register-resident) ----------------
__global__ __launch_bounds__(1024) void scan_k(int* __restrict__ cnt_cur, int* __restrict__ off){
  int t = threadIdx.x;
  int base = t * SCAN_CH;
  int v[SCAN_CH];
  #pragma unroll
  for (int j = 0; j < SCAN_CH; ++j){
    int idx = base + j;
    v[j] = (idx < NN) ? cnt_cur[idx] : 0;
  }
  int s = 0;
  #pragma unroll
  for (int j = 0; j < SCAN_CH; ++j) s += v[j];
  __shared__ int ls[1024];
  ls[t] = s; __syncthreads();
  for (int ofs = 1; ofs < 1024; ofs <<= 1){
    int u = (t >= ofs) ? ls[t - ofs] : 0;
    __syncthreads();
    ls[t] += u;
    __syncthreads();
  }
  int run = (t == 0) ? 0 : ls[t-1];
  #pragma unroll
  for (int j = 0; j < SCAN_CH; ++j){
    int idx = base + j;
    if (idx < NN){
      off[idx] = run;
      cnt_cur[idx] = run;
      run += v[j];
    }
  }
  if (t == 1023) off[NN] = ls[1023];
}

__global__ void fill_k(const int* __restrict__ src, const int* __restrict__ dst,
                       int* __restrict__ cur, int* __restrict__ csrc, int E){
  int e = blockIdx.x*256 + threadIdx.x;
  if (e < E){
    int p = atomicAdd(&cur[dst[e]], 1);
    csrc[p] = src[e];
  }
}

// ---------------- fused layer 1: agg6 + GraphConv(6->128) + relu ----------------
__global__ __launch_bounds__(256) void layer1_k(
    const float* __restrict__ x, const int* __restrict__ off,
    const int* __restrict__ csrc, const float* __restrict__ w1r,
    const float* __restrict__ w1n, const float* __restrict__ b1,
    ushort* __restrict__ h1)
{
  __shared__ float aggs[2][6];
  int slot = threadIdx.x >> 7, c = threadIdx.x & 127;
  int i = blockIdx.x*2 + slot;
  if (c < 6){
    float s = 0.f;
    int e1 = off[i+1];
    for (int j = off[i]; j < e1; ++j) s += x[(size_t)csrc[j]*6 + c];
    aggs[slot][c] = s;
  }
  __syncthreads();
  float s = b1[c];
  #pragma unroll
  for (int f = 0; f < 6; ++f){
    s = fmaf(x[i*6+f],    w1r[f*128+c], s);
    s = fmaf(aggs[slot][f], w1n[f*128+c], s);
  }
  h1[(size_t)i*128 + c] = f2bf(fmaxf(s, 0.f));
}

// ---------------- fused QKVS GEMM: q,k,v -> fp8 | skip -> bf16 ------------------
// LDS-staged A and B (round-7 structure); conflict-free bf16 epilogue tile with
// fp8 conversion during coalesced copy-out.
__global__ __launch_bounds__(256) void qkvs_k(
    const ushort* __restrict__ A, const ushort* __restrict__ BT,
    const float* __restrict__ bq, const float* __restrict__ bk,
    const float* __restrict__ bv, const float* __restrict__ bs,
    u8* __restrict__ cq, u8* __restrict__ ckv,
    ushort* __restrict__ cs, int M)
{
  __shared__ ushort smem[2*128*72];          // As | Bs; reused as epilogue tile
  ushort* Asm = smem;
  ushort* Bsm = smem + 128*72;
  int tid  = threadIdx.x;
  int lane = tid & 63;
  int wid  = tid >> 6;
  int wr = wid >> 1, wc = wid & 1;
  int rowbase = blockIdx.y * 128;
  int seg = blockIdx.x >> 2;
  const float* bias = (seg == 0) ? bq : (seg == 1) ? bk : (seg == 2) ? bv : bs;
  int colloc = (blockIdx.x & 3) * 128;
  int lr = lane & 15, lk = (lane >> 4) * 8;

  f32x4 acc[4][4] = {};

  for (int k0 = 0; k0 < 128; k0 += 64){
    #pragma unroll
    for (int i = 0; i < 4; ++i){
      int c = tid + i*256;
      int r = c >> 3, col8 = (c & 7) * 8;
      int row = rowbase + r;
      bf16x8 av = (bf16x8)0;
      if (row < M) av = *reinterpret_cast<const bf16x8*>(A + (size_t)row*128 + k0 + col8);
      *reinterpret_cast<bf16x8*>(&Asm[r*72 + col8]) = av;
      *reinterpret_cast<bf16x8*>(&Bsm[r*72 + col8]) =
          *reinterpret_cast<const bf16x8*>(BT + (size_t)(blockIdx.x*128 + r)*128 + k0 + col8);
    }
    __syncthreads();
    #pragma unroll
    for (int ks = 0; ks < 64; ks += 32){
      bf16x8 af[4], bfr[4];
      #pragma unroll
      for (int i = 0; i < 4; ++i)
        af[i] = *reinterpret_cast<const bf16x8*>(&Asm[(wr*64 + i*16 + lr)*72 + ks + lk]);
      #pragma unroll
      for (int j = 0; j < 4; ++j)
        bfr[j] = *reinterpret_cast<const bf16x8*>(&Bsm[(wc*64 + j*16 + lr)*72 + ks + lk]);
      #pragma unroll
      for (int i = 0; i < 4; ++i)
        #pragma unroll
        for (int j = 0; j < 4; ++j)
          acc[i][j] = __builtin_amdgcn_mfma_f32_16x16x32_bf16(af[i], bfr[j], acc[i][j], 0, 0, 0);
    }
    __syncthreads();
  }

  // unified bf16 epilogue tile [128][136] ushort = 34816B (fits in smem)
  int rq = lane >> 4;
  #pragma unroll
  for (int i = 0; i < 4; ++i)
    #pragma unroll
    for (int r = 0; r < 4; ++r){
      int lrow = wr*64 + i*16 + rq*4 + r;
      #pragma unroll
      for (int j = 0; j < 4; ++j){
        int lcol = wc*64 + j*16 + lr;
        smem[lrow*136 + lcol] = f2bf(acc[i][j][r] + bias[colloc + lcol]);
      }
    }
  __syncthreads();

  if (seg <= 2){
    u8* Cb; int ldb, cb;
    if (seg == 0){ Cb = cq;  ldb = 512;  cb = colloc; }
    else         { Cb = ckv; ldb = 1024; cb = (seg == 1 ? 0 : 512) + colloc; }
    #pragma unroll
    for (int t = tid; t < 2048; t += 256){
      int r = t >> 4, s8 = (t & 15) * 8;
      int row = rowbase + r;
      if (row < M){
        bf16x8 hv = *reinterpret_cast<const bf16x8*>(&smem[r*136 + s8]);
        unsigned int lo = 0, hi = 0;
        lo = __builtin_amdgcn_cvt_pk_fp8_f32(bf2f((ushort)hv[0]), bf2f((ushort)hv[1]), lo, false);
        lo = __builtin_amdgcn_cvt_pk_fp8_f32(bf2f((ushort)hv[2]), bf2f((ushort)hv[3]), lo, true);
        hi = __builtin_amdgcn_cvt_pk_fp8_f32(bf2f((ushort)hv[4]), bf2f((ushort)hv[5]), hi, false);
        hi = __builtin_amdgcn_cvt_pk_fp8_f32(bf2f((ushort)hv[6]), bf2f((ushort)hv[7]), hi, true);
        uint2 o; o.x = lo; o.y = hi;
        *reinterpret_cast<uint2*>(Cb + (size_t)row*ldb + cb + s8) = o;
      }
    }
  } else {
    #pragma unroll
    for (int t = tid; t < 2048; t += 256){
      int r = t >> 4, s8 = (t & 15) * 8;
      int row = rowbase + r;
      if (row < M)
        *reinterpret_cast<bf16x8*>(cs + (size_t)row*512 + colloc + s8) =
            *reinterpret_cast<const bf16x8*>(&smem[r*136 + s8]);
    }
  }
}

// ---------------- 64-row-tile bf16 MFMA GEMM (lin1), LDS-staged B ---------------
__global__ __launch_bounds__(256) void bgemm64_k(
    const ushort* __restrict__ A1, int lda1, const ushort* __restrict__ B1T, int K1,
    const float* __restrict__ bias, ushort* __restrict__ C, int M, int N)
{
  __shared__ ushort As[64][72];
  __shared__ ushort Bs[128][72];
  int tid  = threadIdx.x;
  int lane = tid & 63;
  int wid  = tid >> 6;
  int wr = wid >> 1, wc = wid & 1;
  int rowbase = blockIdx.y * 64;
  int colbase = blockIdx.x * 128;
  int lr = lane & 15, lk = (lane >> 4) * 8;

  f32x4 acc[2][4] = {};

  for (int k0 = 0; k0 < K1; k0 += 64){
    #pragma unroll
    for (int i = 0; i < 2; ++i){
      int c = tid + i*256;
      int r = c >> 3, col8 = (c & 7) * 8;
      int row = rowbase + r;
      bf16x8 av = (bf16x8)0;
      if (row < M) av = *reinterpret_cast<const bf16x8*>(A1 + (size_t)row*lda1 + k0 + col8);
      *reinterpret_cast<bf16x8*>(&As[r][col8]) = av;
    }
    #pragma unroll
    for (int i = 0; i < 4; ++i){
      int c = tid + i*256;
      int r = c >> 3, col8 = (c & 7) * 8;
      *reinterpret_cast<bf16x8*>(&Bs[r][col8]) =
          *reinterpret_cast<const bf16x8*>(B1T + (size_t)(colbase + r)*K1 + k0 + col8);
    }
    __syncthreads();
    #pragma unroll
    for (int ks = 0; ks < 64; ks += 32){
      bf16x8 af[2], bfr[4];
      #pragma unroll
      for (int i = 0; i < 2; ++i)
        af[i] = *reinterpret_cast<const bf16x8*>(&As[wr*32 + i*16 + lr][ks + lk]);
      #pragma unroll
      for (int j = 0; j < 4; ++j)
        bfr[j] = *reinterpret_cast<const bf16x8*>(&Bs[wc*64 + j*16 + lr][ks + lk]);
      #pragma unroll
      for (int i = 0; i < 2; ++i)
        #pragma unroll
        for (int j = 0; j < 4; ++j)
          acc[i][j] = __builtin_amdgcn_mfma_f32_16x16x32_bf16(af[i], bfr[j], acc[i][j], 0, 0, 0);
    }
    __syncthreads();
  }

  int rq = lane >> 4;
  #pragma unroll
  for (int i = 0; i < 2; ++i){
    #pragma unroll
    for (int r = 0; r < 4; ++r){
      int row = rowbase + wr*32 + i*16 + rq*4 + r;
      if (row >= M) continue;
      #pragma unroll
      for (int j = 0; j < 4; ++j){
        int col = colbase + wc*64 + j*16 + lr;
        if (col >= N) continue;
        float v = fmaxf(acc[i][j][r] + bias[col], 0.f);
        C[(size_t)row*N + col] = f2bf(v);
      }
    }
  }
}

// ---------------- fused GraphConv: out = relu(h@Wr + agg(h)@Wn + b + h) ---------
// B direct from L2 (hoistable, sync-free unrolled K loop).
__global__ __launch_bounds__(256) void gconv_k(
    const ushort* __restrict__ h, const ushort* __restrict__ WrT,
    const ushort* __restrict__ WnT, const float* __restrict__ bias,
    const int* __restrict__ off, const int* __restrict__ csrc,
    ushort* __restrict__ out, int M)
{
  __shared__ ushort As1[64][136];
  __shared__ ushort As2[64][136];
  int tid = threadIdx.x, lane = tid & 63, wid = tid >> 6;
  int wr = wid >> 1, wc = wid & 1;
  int rowbase = blockIdx.x * 64;
  int lr = lane & 15, lk = (lane >> 4) * 8;

  #pragma unroll
  for (int it = 0; it < 4; ++it){
    int c = tid + it*256;
    int r = c >> 4, col8 = (c & 15) * 8;
    int row = rowbase + r;
    bf16x8 av = (bf16x8)0;
    if (row < M) av = *reinterpret_cast<const bf16x8*>(h + (size_t)row*128 + col8);
    *reinterpret_cast<bf16x8*>(&As1[r][col8]) = av;
  }
  {
    int r = tid >> 2, sl = tid & 3;
    int row = rowbase + r;
    float a[32] = {};
    if (row < M){
      int e1 = off[row+1];
      for (int j = off[row]; j < e1; ++j){
        const ushort* hp = h + (size_t)csrc[j]*128 + sl*32;
        #pragma unroll
        for (int u = 0; u < 4; ++u){
          bf16x8 hv = *reinterpret_cast<const bf16x8*>(hp + u*8);
          #pragma unroll
          for (int p = 0; p < 8; ++p) a[u*8+p] += bf2f((ushort)hv[p]);
        }
      }
    }
    #pragma unroll
    for (int u = 0; u < 4; ++u){
      bf16x8 o;
      #pragma unroll
      for (int p = 0; p < 8; ++p) o[p] = (short)f2bf(a[u*8+p]);
      *reinterpret_cast<bf16x8*>(&As2[r][sl*32 + u*8]) = o;
    }
  }
  __syncthreads();

  f32x4 acc[2][4] = {};
  #pragma unroll
  for (int pass = 0; pass < 2; ++pass){
    const ushort* BT = pass ? WnT : WrT;
    #pragma unroll
    for (int kk = 0; kk < 128; kk += 32){
      bf16x8 af[2], bfr[4];
      #pragma unroll
      for (int i = 0; i < 2; ++i)
        af[i] = pass
          ? *reinterpret_cast<const bf16x8*>(&As2[wr*32 + i*16 + lr][kk + lk])
          : *reinterpret_cast<const bf16x8*>(&As1[wr*32 + i*16 + lr][kk + lk]);
      #pragma unroll
      for (int j = 0; j < 4; ++j)
        bfr[j] = *reinterpret_cast<const bf16x8*>(
            BT + (size_t)(wc*64 + j*16 + lr)*128 + kk + lk);
      #pragma unroll
      for (int i = 0; i < 2; ++i)
        #pragma unroll
        for (int j = 0; j < 4; ++j)
          acc[i][j] = __builtin_amdgcn_mfma_f32_16x16x32_bf16(af[i], bfr[j], acc[i][j], 0, 0, 0);
    }
  }

  int rq = lane >> 4;
  #pragma unroll
  for (int i = 0; i < 2; ++i){
    #pragma unroll
    for (int r = 0; r < 4; ++r){
      int lrow = wr*32 + i*16 + rq*4 + r;
      int row = rowbase + lrow;
      if (row >= M) continue;
      #pragma unroll
      for (int j = 0; j < 4; ++j){
        int col = wc*64 + j*16 + lr;
        float v = acc[i][j][r] + bias[col] + bf2f(As1[lrow][col]);
        out[(size_t)row*128 + col] = f2bf(fmaxf(v, 0.f));
      }
    }
  }
}

// ---------------- fused attention: fp8 q + fp8 kv gather, 1 wave/node -----------
__global__ __launch_bounds__(256) void attn_k(
    const u8* __restrict__ q, const u8* __restrict__ kv,
    ushort* __restrict__ s_io,
    const int* __restrict__ off, const int* __restrict__ csrc)
{
  int lane = threadIdx.x & 63;
  int i = blockIdx.x*4 + (threadIdx.x >> 6);
  uint2 qv = *reinterpret_cast<const uint2*>(q + (size_t)i*512 + lane*8);
  f32x2 q01 = __builtin_amdgcn_cvt_pk_f32_fp8(qv.x, false);
  f32x2 q23 = __builtin_amdgcn_cvt_pk_f32_fp8(qv.x, true);
  f32x2 q45 = __builtin_amdgcn_cvt_pk_f32_fp8(qv.y, false);
  f32x2 q67 = __builtin_amdgcn_cvt_pk_f32_fp8(qv.y, true);
  float qf[8] = {q01[0], q01[1], q23[0], q23[1], q45[0], q45[1], q67[0], q67[1]};

  float d = 0.f, acc[8] = {};
  int e0 = off[i], e1 = off[i+1];
  uint2 kA, vA, kB, vB;
  if (e0 < e1){
    const u8* r = kv + (size_t)csrc[e0]*1024 + lane*8;
    kA = *reinterpret_cast<const uint2*>(r);
    vA = *reinterpret_cast<const uint2*>(r + 512);
  }
  if (e0 + 1 < e1){
    const u8* r = kv + (size_t)csrc[e0+1]*1024 + lane*8;
    kB = *reinterpret_cast<const uint2*>(r);
    vB = *reinterpret_cast<const uint2*>(r + 512);
  }
  for (int j = e0; j < e1; ++j){
    uint2 kc = kA, vc = vA;
    kA = kB; vA = vB;
    if (j + 2 < e1){
      const u8* r = kv + (size_t)csrc[j+2]*1024 + lane*8;
      kB = *reinterpret_cast<const uint2*>(r);
      vB = *reinterpret_cast<const uint2*>(r + 512);
    }
    f32x2 k01 = __builtin_amdgcn_cvt_pk_f32_fp8(kc.x, false);
    f32x2 k23 = __builtin_amdgcn_cvt_pk_f32_fp8(kc.x, true);
    f32x2 k45 = __builtin_amdgcn_cvt_pk_f32_fp8(kc.y, false);
    f32x2 k67 = __builtin_amdgcn_cvt_pk_f32_fp8(kc.y, true);
    float t;
    t = qf[0] * k01[0];
    t = fmaf(qf[1], k01[1], t);
    t = fmaf(qf[2], k23[0], t);
    t = fmaf(qf[3], k23[1], t);
    t = fmaf(qf[4], k45[0], t);
    t = fmaf(qf[5], k45[1], t);
    t = fmaf(qf[6], k67[0], t);
    t = fmaf(qf[7], k67[1], t);
    t += __shfl_xor(t, 1);
    t += __shfl_xor(t, 2);
    t += __shfl_xor(t, 4);
    t += __shfl_xor(t, 8);                       // 16-lane head group
    float w = __expf(t * 0.08838834764831845f);  // logits tiny: no max-shift needed
    d += w;
    f32x2 v01 = __builtin_amdgcn_cvt_pk_f32_fp8(vc.x, false);
    f32x2 v23 = __builtin_amdgcn_cvt_pk_f32_fp8(vc.x, true);
    f32x2 v45 = __builtin_amdgcn_cvt_pk_f32_fp8(vc.y, false);
    f32x2 v67 = __builtin_amdgcn_cvt_pk_f32_fp8(vc.y, true);
    acc[0] = fmaf(w, v01[0], acc[0]);
    acc[1] = fmaf(w, v01[1], acc[1]);
    acc[2] = fmaf(w, v23[0], acc[2]);
    acc[3] = fmaf(w, v23[1], acc[3]);
    acc[4] = fmaf(w, v45[0], acc[4]);
    acc[5] = fmaf(w, v45[1], acc[5]);
    acc[6] = fmaf(w, v67[0], acc[6]);
    acc[7] = fmaf(w, v67[1], acc[7]);
  }
  float inv = (d > 0.f) ? 1.f/d : 0.f;
  ushort* rowp = s_io + (size_t)i*512 + lane*8;
  bf16x8 sk8 = *reinterpret_cast<const bf16x8*>(rowp);
  bf16x8 o8;
  #pragma unroll
  for (int p = 0; p < 8; ++p)
    o8[p] = (short)f2bf(fmaxf(bf2f((ushort)sk8[p]) + acc[p]*inv, 0.f));
  *reinterpret_cast<bf16x8*>(rowp) = o8;
}

// ---------------- fused pooling + frame mean + classifier ----------------
__global__ __launch_bounds__(256) void fc_k(const ushort* __restrict__ h,
    const float* __restrict__ fcw, const float* __restrict__ fcb,
    float* __restrict__ out)
{
  int s = blockIdx.x;
  int t = threadIdx.x;
  int c = t & 127, g = t >> 7;
  float sum = 0.f;
  for (int r = g; r < 1625; r += 2)
    sum += bf2f(h[((size_t)s*1625 + r)*128 + c]);
  __shared__ float zs[2][128];
  zs[g][c] = sum; __syncthreads();
  if (t < 128) zs[0][t] = (zs[0][t] + zs[1][t]) * (1.0f/1625.0f);
  __syncthreads();
  if (t < 7){
    float o = fcb[t];
    for (int k2 = 0; k2 < 128; ++k2) o = fmaf(zs[0][k2], fcw[k2*7 + t], o);
    out[s*7 + t] = o;
  }
}

// ---------------- launcher ----------------
extern "C" void kernel_launch(void* const* d_in, const int* in_sizes, int n_in,
                              void* d_out, int out_size, void* d_ws, size_t ws_size,
                              hipStream_t stream)
{
  const float* x     = (const float*)d_in[0];
  const int*   ei    = (const int*)  d_in[1];
  const float* w1r   = (const float*)d_in[3];
  const float* w1n   = (const float*)d_in[4];
  const float* b1    = (const float*)d_in[5];
  const float* wq    = (const float*)d_in[6];
  const float* bq    = (const float*)d_in[7];
  const float* wk    = (const float*)d_in[8];
  const float* bk    = (const float*)d_in[9];
  const float* wv    = (const float*)d_in[10];
  const float* bv    = (const float*)d_in[11];
  const float* wskip = (const float*)d_in[12];
  const float* bskip = (const float*)d_in[13];
  const float* skw   = (const float*)d_in[14];
  const float* lin1w = (const float*)d_in[15];
  const float* lin1b = (const float*)d_in[16];
  const float* l2r   = (const float*)d_in[17];
  const float* l2n   = (const float*)d_in[18];
  const float* l2b   = (const float*)d_in[19];
  const float* l3r   = (const float*)d_in[20];
  const float* l3n   = (const float*)d_in[21];
  const float* l3b   = (const float*)d_in[22];
  const float* fcw   = (const float*)d_in[23];
  const float* fcb   = (const float*)d_in[24];
  float* out = (float*)d_out;

  const int* src = ei;
  const int* dst = ei + NE;

  char* base = (char*)d_ws;
  size_t o = 0;
  auto alloc = [&](size_t bytes) -> void* {
    o = (o + 255) & ~(size_t)255;
    void* p = base + o; o += bytes; return p;
  };
  int*    cnt     = (int*)   alloc((size_t)NN*4);
  int*    off     = (int*)   alloc((size_t)(NN+1)*4);
  int*    csrc    = (int*)   alloc((size_t)NE*4);
  ushort* h1      = (ushort*)alloc((size_t)NN*128*2);
  ushort* wbuf    = (ushort*)alloc((size_t)393216*2);
  u8*     bufQ8   = (u8*)    alloc((size_t)NN*512);     // fp8 q
  u8*     bufKV   = (u8*)    alloc((size_t)NN*1024);    // fp8 k|v
  ushort* bufS    = (ushort*)alloc((size_t)NN*512*2);   // skip -> h2 -> h5
  ushort* hbuf    = (ushort*)alloc((size_t)NN*256*2);   // h3 | h4
  (void)ws_size; (void)in_sizes; (void)n_in; (void)out_size;

  const ushort* lin1T = wbuf + 262144;
  const ushort* l2rT  = wbuf + 327680;
  const ushort* l2nT  = wbuf + 344064;
  const ushort* l3rT  = wbuf + 360448;
  const ushort* l3nT  = wbuf + 376832;

  ushort* h3 = hbuf;
  ushort* h4 = hbuf + (size_t)NN*128;
  ushort* h5 = bufS;

  // CSR + weight prep
  hipMemsetAsync(cnt, 0, (size_t)NN*4, stream);
  cp_k<<<CNT_BLOCKS + 1536, 256, 0, stream>>>(dst, cnt,
      wq, wk, wv, wskip, skw, lin1w, l2r, l2n, l3r, l3n, wbuf);
  scan_k<<<1, 1024, 0, stream>>>(cnt, off);
  fill_k<<<(NE+255)/256, 256, 0, stream>>>(src, dst, cnt, csrc, NE);

  // layer 1 (fused agg + conv)
  layer1_k<<<NN/2, 256, 0, stream>>>(x, off, csrc, w1r, w1n, b1, h1);

  // fused q|k|v|skip projection (q,k,v output as fp8)
  {
    dim3 g(16, (NN+127)/128);
    qkvs_k<<<g, 256, 0, stream>>>(h1, wbuf, bq, bk, bv, bskip,
                                  bufQ8, bufKV, bufS, NN);
  }

  // fused attention -> h2 in bufS
  attn_k<<<NN/4, 256, 0, stream>>>(bufQ8, bufKV, bufS, off, csrc);

  // lin1: h3 = relu(h2 @ lin1_w + lin1_b)
  {
    dim3 g(1, (NN+63)/64);
    bgemm64_k<<<g, 256, 0, stream>>>(bufS, 512, lin1T, 512, lin1b, h3, NN, 128);
  }

  // GraphConv residual layers (fused gather + dual GEMM + residual + relu)
  gconv_k<<<(NN+63)/64, 256, 0, stream>>>(h3, l2rT, l2nT, l2b, off, csrc, h4, NN);
  gconv_k<<<(NN+63)/64, 256, 0, stream>>>(h4, l3rT, l3nT, l3b, off, csrc, h5, NN);

  // pool + frame mean + classify
  fc_k<<<16, 256, 0, stream>>>(h5, fcw, fcb, out);
}

// Round 10
// 287.572 us; speedup vs baseline: 1.6010x; 1.6010x over previous
//
#include <hip/hip_runtime.h>
#include <math.h>

#define NN 26000
#define NE 208000
#define SCAN_CH 26        // ceil(NN/1024), compile-time
#define CNT_BLOCKS 813    // ceil(NE/256)

typedef __attribute__((ext_vector_type(8))) short bf16x8;
typedef __attribute__((ext_vector_type(4))) float f32x4;
typedef __attribute__((ext_vector_type(2))) float f32x2;
typedef unsigned char u8;

__device__ __forceinline__ float bf2f(ushort u){
  union { unsigned int i; float f; } w; w.i = ((unsigned int)u) << 16; return w.f;
}
__device__ __forceinline__ ushort f2bf(float f){
  union { float f; unsigned int i; } w; w.f = f;
  unsigned int u = w.i + 0x7fffu + ((w.i >> 16) & 1u);  // RNE
  return (ushort)(u >> 16);
}

// ---------------- fused count + weight-prep ----------------
__global__ void cp_k(const int* __restrict__ dst, int* __restrict__ cnt,
                     const float* __restrict__ wq, const float* __restrict__ wk,
                     const float* __restrict__ wv, const float* __restrict__ wskip,
                     const float* __restrict__ skw, const float* __restrict__ lin1w,
                     const float* __restrict__ l2r, const float* __restrict__ l2n,
                     const float* __restrict__ l3r, const float* __restrict__ l3n,
                     ushort* __restrict__ wbuf){
  if (blockIdx.x < CNT_BLOCKS){
    int e = blockIdx.x*256 + threadIdx.x;
    if (e < NE) atomicAdd(&cnt[dst[e]], 1);
    return;
  }
  int idx = (blockIdx.x - CNT_BLOCKS)*256 + threadIdx.x;
  if (idx >= 393216) return;
  float v;
  if (idx < 262144){
    int seg = idx >> 16;
    int local = idx & 65535;
    int n = local >> 7, kk = local & 127;
    const float* w = (seg == 0) ? wq : (seg == 1) ? wk : (seg == 2) ? wv : wskip;
    v = w[kk*512 + n];
    if (seg == 3) v += skw[kk*512 + n];
  } else if (idx < 327680){
    int local = idx - 262144;
    int n = local >> 9, kk = local & 511;
    v = lin1w[kk*128 + n];
  } else {
    int rem = idx - 327680;
    int seg = rem >> 14;
    int local = rem & 16383;
    int n = local >> 7, kk = local & 127;
    const float* w = (seg == 0) ? l2r : (seg == 1) ? l2n : (seg == 2) ? l3r : l3n;
    v = w[kk*128 + n];
  }
  wbuf[idx] = f2bf(v);
}

// ---------------- scan (single block, register-resident) ----------------
__global__ __launch_bounds__(1024) void scan_k(int* __restrict__ cnt_cur, int* __restrict__ off){
  int t = threadIdx.x;
  int base = t * SCAN_CH;
  int v[SCAN_CH];
  #pragma unroll
  for (int j = 0; j < SCAN_CH; ++j){
    int idx = base + j;
    v[j] = (idx < NN) ? cnt_cur[idx] : 0;
  }
  int s = 0;
  #pragma unroll
  for (int j = 0; j < SCAN_CH; ++j) s += v[j];
  __shared__ int ls[1024];
  ls[t] = s; __syncthreads();
  for (int ofs = 1; ofs < 1024; ofs <<= 1){
    int u = (t >= ofs) ? ls[t - ofs] : 0;
    __syncthreads();
    ls[t] += u;
    __syncthreads();
  }
  int run = (t == 0) ? 0 : ls[t-1];
  #pragma unroll
  for (int j = 0; j < SCAN_CH; ++j){
    int idx = base + j;
    if (idx < NN){
      off[idx] = run;
      cnt_cur[idx] = run;
      run += v[j];
    }
  }
  if (t == 1023) off[NN] = ls[1023];
}

__global__ void fill_k(const int* __restrict__ src, const int* __restrict__ dst,
                       int* __restrict__ cur, int* __restrict__ csrc, int E){
  int e = blockIdx.x*256 + threadIdx.x;
  if (e < E){
    int p = atomicAdd(&cur[dst[e]], 1);
    csrc[p] = src[e];
  }
}

// ---------------- fused layer 1: agg6 + GraphConv(6->128) + relu ----------------
__global__ __launch_bounds__(256) void layer1_k(
    const float* __restrict__ x, const int* __restrict__ off,
    const int* __restrict__ csrc, const float* __restrict__ w1r,
    const float* __restrict__ w1n, const float* __restrict__ b1,
    ushort* __restrict__ h1)
{
  __shared__ float aggs[2][6];
  int slot = threadIdx.x >> 7, c = threadIdx.x & 127;
  int i = blockIdx.x*2 + slot;
  if (c < 6){
    float s = 0.f;
    int e1 = off[i+1];
    for (int j = off[i]; j < e1; ++j) s += x[(size_t)csrc[j]*6 + c];
    aggs[slot][c] = s;
  }
  __syncthreads();
  float s = b1[c];
  #pragma unroll
  for (int f = 0; f < 6; ++f){
    s = fmaf(x[i*6+f],    w1r[f*128+c], s);
    s = fmaf(aggs[slot][f], w1n[f*128+c], s);
  }
  h1[(size_t)i*128 + c] = f2bf(fmaxf(s, 0.f));
}

// ---------------- fused QKVS GEMM: q,k,v -> fp8 | skip -> bf16 ------------------
__global__ __launch_bounds__(256) void qkvs_k(
    const ushort* __restrict__ A, const ushort* __restrict__ BT,
    const float* __restrict__ bq, const float* __restrict__ bk,
    const float* __restrict__ bv, const float* __restrict__ bs,
    u8* __restrict__ cq, u8* __restrict__ ckv,
    ushort* __restrict__ cs, int M)
{
  __shared__ ushort smem[2*128*72];          // As | Bs; reused as epilogue tile
  ushort* Asm = smem;
  ushort* Bsm = smem + 128*72;
  int tid  = threadIdx.x;
  int lane = tid & 63;
  int wid  = tid >> 6;
  int wr = wid >> 1, wc = wid & 1;
  int rowbase = blockIdx.y * 128;
  int seg = blockIdx.x >> 2;
  const float* bias = (seg == 0) ? bq : (seg == 1) ? bk : (seg == 2) ? bv : bs;
  int colloc = (blockIdx.x & 3) * 128;
  int lr = lane & 15, lk = (lane >> 4) * 8;

  f32x4 acc[4][4] = {};

  for (int k0 = 0; k0 < 128; k0 += 64){
    #pragma unroll
    for (int i = 0; i < 4; ++i){
      int c = tid + i*256;
      int r = c >> 3, col8 = (c & 7) * 8;
      int row = rowbase + r;
      bf16x8 av = (bf16x8)0;
      if (row < M) av = *reinterpret_cast<const bf16x8*>(A + (size_t)row*128 + k0 + col8);
      *reinterpret_cast<bf16x8*>(&Asm[r*72 + col8]) = av;
      *reinterpret_cast<bf16x8*>(&Bsm[r*72 + col8]) =
          *reinterpret_cast<const bf16x8*>(BT + (size_t)(blockIdx.x*128 + r)*128 + k0 + col8);
    }
    __syncthreads();
    #pragma unroll
    for (int ks = 0; ks < 64; ks += 32){
      bf16x8 af[4], bfr[4];
      #pragma unroll
      for (int i = 0; i < 4; ++i)
        af[i] = *reinterpret_cast<const bf16x8*>(&Asm[(wr*64 + i*16 + lr)*72 + ks + lk]);
      #pragma unroll
      for (int j = 0; j < 4; ++j)
        bfr[j] = *reinterpret_cast<const bf16x8*>(&Bsm[(wc*64 + j*16 + lr)*72 + ks + lk]);
      #pragma unroll
      for (int i = 0; i < 4; ++i)
        #pragma unroll
        for (int j = 0; j < 4; ++j)
          acc[i][j] = __builtin_amdgcn_mfma_f32_16x16x32_bf16(af[i], bfr[j], acc[i][j], 0, 0, 0);
    }
    __syncthreads();
  }

  // unified bf16 epilogue tile [128][136] ushort
  int rq = lane >> 4;
  #pragma unroll
  for (int i = 0; i < 4; ++i)
    #pragma unroll
    for (int r = 0; r < 4; ++r){
      int lrow = wr*64 + i*16 + rq*4 + r;
      #pragma unroll
      for (int j = 0; j < 4; ++j){
        int lcol = wc*64 + j*16 + lr;
        smem[lrow*136 + lcol] = f2bf(acc[i][j][r] + bias[colloc + lcol]);
      }
    }
  __syncthreads();

  if (seg <= 2){
    u8* Cb; int ldb, cb;
    if (seg == 0){ Cb = cq;  ldb = 512;  cb = colloc; }
    else         { Cb = ckv; ldb = 1024; cb = (seg == 1 ? 0 : 512) + colloc; }
    #pragma unroll
    for (int t = tid; t < 2048; t += 256){
      int r = t >> 4, s8 = (t & 15) * 8;
      int row = rowbase + r;
      if (row < M){
        bf16x8 hv = *reinterpret_cast<const bf16x8*>(&smem[r*136 + s8]);
        unsigned int lo = 0, hi = 0;
        lo = __builtin_amdgcn_cvt_pk_fp8_f32(bf2f((ushort)hv[0]), bf2f((ushort)hv[1]), lo, false);
        lo = __builtin_amdgcn_cvt_pk_fp8_f32(bf2f((ushort)hv[2]), bf2f((ushort)hv[3]), lo, true);
        hi = __builtin_amdgcn_cvt_pk_fp8_f32(bf2f((ushort)hv[4]), bf2f((ushort)hv[5]), hi, false);
        hi = __builtin_amdgcn_cvt_pk_fp8_f32(bf2f((ushort)hv[6]), bf2f((ushort)hv[7]), hi, true);
        uint2 o; o.x = lo; o.y = hi;
        *reinterpret_cast<uint2*>(Cb + (size_t)row*ldb + cb + s8) = o;
      }
    }
  } else {
    #pragma unroll
    for (int t = tid; t < 2048; t += 256){
      int r = t >> 4, s8 = (t & 15) * 8;
      int row = rowbase + r;
      if (row < M)
        *reinterpret_cast<bf16x8*>(cs + (size_t)row*512 + colloc + s8) =
            *reinterpret_cast<const bf16x8*>(&smem[r*136 + s8]);
    }
  }
}

// ---------------- 64-row-tile bf16 MFMA GEMM (lin1), LDS-staged B ---------------
__global__ __launch_bounds__(256) void bgemm64_k(
    const ushort* __restrict__ A1, int lda1, const ushort* __restrict__ B1T, int K1,
    const float* __restrict__ bias, ushort* __restrict__ C, int M, int N)
{
  __shared__ ushort As[64][72];
  __shared__ ushort Bs[128][72];
  int tid  = threadIdx.x;
  int lane = tid & 63;
  int wid  = tid >> 6;
  int wr = wid >> 1, wc = wid & 1;
  int rowbase = blockIdx.y * 64;
  int colbase = blockIdx.x * 128;
  int lr = lane & 15, lk = (lane >> 4) * 8;

  f32x4 acc[2][4] = {};

  for (int k0 = 0; k0 < K1; k0 += 64){
    #pragma unroll
    for (int i = 0; i < 2; ++i){
      int c = tid + i*256;
      int r = c >> 3, col8 = (c & 7) * 8;
      int row = rowbase + r;
      bf16x8 av = (bf16x8)0;
      if (row < M) av = *reinterpret_cast<const bf16x8*>(A1 + (size_t)row*lda1 + k0 + col8);
      *reinterpret_cast<bf16x8*>(&As[r][col8]) = av;
    }
    #pragma unroll
    for (int i = 0; i < 4; ++i){
      int c = tid + i*256;
      int r = c >> 3, col8 = (c & 7) * 8;
      *reinterpret_cast<bf16x8*>(&Bs[r][col8]) =
          *reinterpret_cast<const bf16x8*>(B1T + (size_t)(colbase + r)*K1 + k0 + col8);
    }
    __syncthreads();
    #pragma unroll
    for (int ks = 0; ks < 64; ks += 32){
      bf16x8 af[2], bfr[4];
      #pragma unroll
      for (int i = 0; i < 2; ++i)
        af[i] = *reinterpret_cast<const bf16x8*>(&As[wr*32 + i*16 + lr][ks + lk]);
      #pragma unroll
      for (int j = 0; j < 4; ++j)
        bfr[j] = *reinterpret_cast<const bf16x8*>(&Bs[wc*64 + j*16 + lr][ks + lk]);
      #pragma unroll
      for (int i = 0; i < 2; ++i)
        #pragma unroll
        for (int j = 0; j < 4; ++j)
          acc[i][j] = __builtin_amdgcn_mfma_f32_16x16x32_bf16(af[i], bfr[j], acc[i][j], 0, 0, 0);
    }
    __syncthreads();
  }

  int rq = lane >> 4;
  #pragma unroll
  for (int i = 0; i < 2; ++i){
    #pragma unroll
    for (int r = 0; r < 4; ++r){
      int row = rowbase + wr*32 + i*16 + rq*4 + r;
      if (row >= M) continue;
      #pragma unroll
      for (int j = 0; j < 4; ++j){
        int col = colbase + wc*64 + j*16 + lr;
        if (col >= N) continue;
        float v = fmaxf(acc[i][j][r] + bias[col], 0.f);
        C[(size_t)row*N + col] = f2bf(v);
      }
    }
  }
}

// ---------------- fused GraphConv: out = relu(h@Wr + agg(h)@Wn + b + h) ---------
__global__ __launch_bounds__(256) void gconv_k(
    const ushort* __restrict__ h, const ushort* __restrict__ WrT,
    const ushort* __restrict__ WnT, const float* __restrict__ bias,
    const int* __restrict__ off, const int* __restrict__ csrc,
    ushort* __restrict__ out, int M)
{
  __shared__ ushort As1[64][136];
  __shared__ ushort As2[64][136];
  int tid = threadIdx.x, lane = tid & 63, wid = tid >> 6;
  int wr = wid >> 1, wc = wid & 1;
  int rowbase = blockIdx.x * 64;
  int lr = lane & 15, lk = (lane >> 4) * 8;

  #pragma unroll
  for (int it = 0; it < 4; ++it){
    int c = tid + it*256;
    int r = c >> 4, col8 = (c & 15) * 8;
    int row = rowbase + r;
    bf16x8 av = (bf16x8)0;
    if (row < M) av = *reinterpret_cast<const bf16x8*>(h + (size_t)row*128 + col8);
    *reinterpret_cast<bf16x8*>(&As1[r][col8]) = av;
  }
  {
    int r = tid >> 2, sl = tid & 3;
    int row = rowbase + r;
    float a[32] = {};
    if (row < M){
      int e1 = off[row+1];
      for (int j = off[row]; j < e1; ++j){
        const ushort* hp = h + (size_t)csrc[j]*128 + sl*32;
        #pragma unroll
        for (int u = 0; u < 4; ++u){
          bf16x8 hv = *reinterpret_cast<const bf16x8*>(hp + u*8);
          #pragma unroll
          for (int p = 0; p < 8; ++p) a[u*8+p] += bf2f((ushort)hv[p]);
        }
      }
    }
    #pragma unroll
    for (int u = 0; u < 4; ++u){
      bf16x8 o;
      #pragma unroll
      for (int p = 0; p < 8; ++p) o[p] = (short)f2bf(a[u*8+p]);
      *reinterpret_cast<bf16x8*>(&As2[r][sl*32 + u*8]) = o;
    }
  }
  __syncthreads();

  f32x4 acc[2][4] = {};
  #pragma unroll
  for (int pass = 0; pass < 2; ++pass){
    const ushort* BT = pass ? WnT : WrT;
    #pragma unroll
    for (int kk = 0; kk < 128; kk += 32){
      bf16x8 af[2], bfr[4];
      #pragma unroll
      for (int i = 0; i < 2; ++i)
        af[i] = pass
          ? *reinterpret_cast<const bf16x8*>(&As2[wr*32 + i*16 + lr][kk + lk])
          : *reinterpret_cast<const bf16x8*>(&As1[wr*32 + i*16 + lr][kk + lk]);
      #pragma unroll
      for (int j = 0; j < 4; ++j)
        bfr[j] = *reinterpret_cast<const bf16x8*>(
            BT + (size_t)(wc*64 + j*16 + lr)*128 + kk + lk);
      #pragma unroll
      for (int i = 0; i < 2; ++i)
        #pragma unroll
        for (int j = 0; j < 4; ++j)
          acc[i][j] = __builtin_amdgcn_mfma_f32_16x16x32_bf16(af[i], bfr[j], acc[i][j], 0, 0, 0);
    }
  }

  int rq = lane >> 4;
  #pragma unroll
  for (int i = 0; i < 2; ++i){
    #pragma unroll
    for (int r = 0; r < 4; ++r){
      int lrow = wr*32 + i*16 + rq*4 + r;
      int row = rowbase + lrow;
      if (row >= M) continue;
      #pragma unroll
      for (int j = 0; j < 4; ++j){
        int col = wc*64 + j*16 + lr;
        float v = acc[i][j][r] + bias[col] + bf2f(As1[lrow][col]);
        out[(size_t)row*128 + col] = f2bf(fmaxf(v, 0.f));
      }
    }
  }
}

// ---------------- fused attention: fp8 q + fp8 kv gather, 1 wave/node -----------
__global__ __launch_bounds__(256) void attn_k(
    const u8* __restrict__ q, const u8* __restrict__ kv,
    ushort* __restrict__ s_io,
    const int* __restrict__ off, const int* __restrict__ csrc)
{
  int lane = threadIdx.x & 63;
  int i = blockIdx.x*4 + (threadIdx.x >> 6);
  uint2 qv = *reinterpret_cast<const uint2*>(q + (size_t)i*512 + lane*8);
  f32x2 q01 = __builtin_amdgcn_cvt_pk_f32_fp8(qv.x, false);
  f32x2 q23 = __builtin_amdgcn_cvt_pk_f32_fp8(qv.x, true);
  f32x2 q45 = __builtin_amdgcn_cvt_pk_f32_fp8(qv.y, false);
  f32x2 q67 = __builtin_amdgcn_cvt_pk_f32_fp8(qv.y, true);
  float qf[8] = {q01[0], q01[1], q23[0], q23[1], q45[0], q45[1], q67[0], q67[1]};

  float d = 0.f, acc[8] = {};
  int e0 = off[i], e1 = off[i+1];
  uint2 kA, vA, kB, vB;
  if (e0 < e1){
    const u8* r = kv + (size_t)csrc[e0]*1024 + lane*8;
    kA = *reinterpret_cast<const uint2*>(r);
    vA = *reinterpret_cast<const uint2*>(r + 512);
  }
  if (e0 + 1 < e1){
    const u8* r = kv + (size_t)csrc[e0+1]*1024 + lane*8;
    kB = *reinterpret_cast<const uint2*>(r);
    vB = *reinterpret_cast<const uint2*>(r + 512);
  }
  for (int j = e0; j < e1; ++j){
    uint2 kc = kA, vc = vA;
    kA = kB; vA = vB;
    if (j + 2 < e1){
      const u8* r = kv + (size_t)csrc[j+2]*1024 + lane*8;
      kB = *reinterpret_cast<const uint2*>(r);
      vB = *reinterpret_cast<const uint2*>(r + 512);
    }
    f32x2 k01 = __builtin_amdgcn_cvt_pk_f32_fp8(kc.x, false);
    f32x2 k23 = __builtin_amdgcn_cvt_pk_f32_fp8(kc.x, true);
    f32x2 k45 = __builtin_amdgcn_cvt_pk_f32_fp8(kc.y, false);
    f32x2 k67 = __builtin_amdgcn_cvt_pk_f32_fp8(kc.y, true);
    float t;
    t = qf[0] * k01[0];
    t = fmaf(qf[1], k01[1], t);
    t = fmaf(qf[2], k23[0], t);
    t = fmaf(qf[3], k23[1], t);
    t = fmaf(qf[4], k45[0], t);
    t = fmaf(qf[5], k45[1], t);
    t = fmaf(qf[6], k67[0], t);
    t = fmaf(qf[7], k67[1], t);
    t += __shfl_xor(t, 1);
    t += __shfl_xor(t, 2);
    t += __shfl_xor(t, 4);
    t += __shfl_xor(t, 8);                       // 16-lane head group
    float w = __expf(t * 0.08838834764831845f);  // logits tiny: no max-shift needed
    d += w;
    f32x2 v01 = __builtin_amdgcn_cvt_pk_f32_fp8(vc.x, false);
    f32x2 v23 = __builtin_amdgcn_cvt_pk_f32_fp8(vc.x, true);
    f32x2 v45 = __builtin_amdgcn_cvt_pk_f32_fp8(vc.y, false);
    f32x2 v67 = __builtin_amdgcn_cvt_pk_f32_fp8(vc.y, true);
    acc[0] = fmaf(w, v01[0], acc[0]);
    acc[1] = fmaf(w, v01[1], acc[1]);
    acc[2] = fmaf(w, v23[0], acc[2]);
    acc[3] = fmaf(w, v23[1], acc[3]);
    acc[4] = fmaf(w, v45[0], acc[4]);
    acc[5] = fmaf(w, v45[1], acc[5]);
    acc[6] = fmaf(w, v67[0], acc[6]);
    acc[7] = fmaf(w, v67[1], acc[7]);
  }
  float inv = (d > 0.f) ? 1.f/d : 0.f;
  ushort* rowp = s_io + (size_t)i*512 + lane*8;
  bf16x8 sk8 = *reinterpret_cast<const bf16x8*>(rowp);
  bf16x8 o8;
  #pragma unroll
  for (int p = 0; p < 8; ++p)
    o8[p] = (short)f2bf(fmaxf(bf2f((ushort)sk8[p]) + acc[p]*inv, 0.f));
  *reinterpret_cast<bf16x8*>(rowp) = o8;
}

// ---------------- pooling stage 1: partial row sums ----------------
__global__ __launch_bounds__(256) void fc1_k(const ushort* __restrict__ h,
                                             float* __restrict__ partial){
  int s = blockIdx.x, c0 = blockIdx.y;
  int t = threadIdx.x;
  int c = t & 127, g = t >> 7;
  float sum = 0.f;
  int rend = (c0 + 1) * 125;
  for (int r = c0*125 + g; r < rend; r += 2)
    sum += bf2f(h[((size_t)s*1625 + r)*128 + c]);
  __shared__ float zs[2][128];
  zs[g][c] = sum; __syncthreads();
  if (g == 0) partial[((size_t)s*13 + c0)*128 + c] = zs[0][c] + zs[1][c];
}

// ---------------- pooling stage 2 + classifier ----------------
__global__ __launch_bounds__(128) void fc2_k(const float* __restrict__ partial,
    const float* __restrict__ fcw, const float* __restrict__ fcb,
    float* __restrict__ out)
{
  int s = blockIdx.x;
  int c = threadIdx.x;
  float z = 0.f;
  #pragma unroll
  for (int p = 0; p < 13; ++p) z += partial[((size_t)s*13 + p)*128 + c];
  __shared__ float zs[128];
  zs[c] = z * (1.0f/1625.0f);
  __syncthreads();
  if (c < 7){
    float o = fcb[c];
    for (int k2 = 0; k2 < 128; ++k2) o = fmaf(zs[k2], fcw[k2*7 + c], o);
    out[s*7 + c] = o;
  }
}

// ---------------- launcher ----------------
extern "C" void kernel_launch(void* const* d_in, const int* in_sizes, int n_in,
                              void* d_out, int out_size, void* d_ws, size_t ws_size,
                              hipStream_t stream)
{
  const float* x     = (const float*)d_in[0];
  const int*   ei    = (const int*)  d_in[1];
  const float* w1r   = (const float*)d_in[3];
  const float* w1n   = (const float*)d_in[4];
  const float* b1    = (const float*)d_in[5];
  const float* wq    = (const float*)d_in[6];
  const float* bq    = (const float*)d_in[7];
  const float* wk    = (const float*)d_in[8];
  const float* bk    = (const float*)d_in[9];
  const float* wv    = (const float*)d_in[10];
  const float* bv    = (const float*)d_in[11];
  const float* wskip = (const float*)d_in[12];
  const float* bskip = (const float*)d_in[13];
  const float* skw   = (const float*)d_in[14];
  const float* lin1w = (const float*)d_in[15];
  const float* lin1b = (const float*)d_in[16];
  const float* l2r   = (const float*)d_in[17];
  const float* l2n   = (const float*)d_in[18];
  const float* l2b   = (const float*)d_in[19];
  const float* l3r   = (const float*)d_in[20];
  const float* l3n   = (const float*)d_in[21];
  const float* l3b   = (const float*)d_in[22];
  const float* fcw   = (const float*)d_in[23];
  const float* fcb   = (const float*)d_in[24];
  float* out = (float*)d_out;

  const int* src = ei;
  const int* dst = ei + NE;

  char* base = (char*)d_ws;
  size_t o = 0;
  auto alloc = [&](size_t bytes) -> void* {
    o = (o + 255) & ~(size_t)255;
    void* p = base + o; o += bytes; return p;
  };
  int*    cnt     = (int*)   alloc((size_t)NN*4);
  int*    off     = (int*)   alloc((size_t)(NN+1)*4);
  int*    csrc    = (int*)   alloc((size_t)NE*4);
  float*  partial = (float*) alloc((size_t)16*13*128*4);
  ushort* h1      = (ushort*)alloc((size_t)NN*128*2);
  ushort* wbuf    = (ushort*)alloc((size_t)393216*2);
  u8*     bufQ8   = (u8*)    alloc((size_t)NN*512);     // fp8 q
  u8*     bufKV   = (u8*)    alloc((size_t)NN*1024);    // fp8 k|v
  ushort* bufS    = (ushort*)alloc((size_t)NN*512*2);   // skip -> h2 -> h5
  ushort* hbuf    = (ushort*)alloc((size_t)NN*256*2);   // h3 | h4
  (void)ws_size; (void)in_sizes; (void)n_in; (void)out_size;

  const ushort* lin1T = wbuf + 262144;
  const ushort* l2rT  = wbuf + 327680;
  const ushort* l2nT  = wbuf + 344064;
  const ushort* l3rT  = wbuf + 360448;
  const ushort* l3nT  = wbuf + 376832;

  ushort* h3 = hbuf;
  ushort* h4 = hbuf + (size_t)NN*128;
  ushort* h5 = bufS;

  // CSR + weight prep
  hipMemsetAsync(cnt, 0, (size_t)NN*4, stream);
  cp_k<<<CNT_BLOCKS + 1536, 256, 0, stream>>>(dst, cnt,
      wq, wk, wv, wskip, skw, lin1w, l2r, l2n, l3r, l3n, wbuf);
  scan_k<<<1, 1024, 0, stream>>>(cnt, off);
  fill_k<<<(NE+255)/256, 256, 0, stream>>>(src, dst, cnt, csrc, NE);

  // layer 1 (fused agg + conv)
  layer1_k<<<NN/2, 256, 0, stream>>>(x, off, csrc, w1r, w1n, b1, h1);

  // fused q|k|v|skip projection (q,k,v output as fp8)
  {
    dim3 g(16, (NN+127)/128);
    qkvs_k<<<g, 256, 0, stream>>>(h1, wbuf, bq, bk, bv, bskip,
                                  bufQ8, bufKV, bufS, NN);
  }

  // fused attention -> h2 in bufS
  attn_k<<<NN/4, 256, 0, stream>>>(bufQ8, bufKV, bufS, off, csrc);

  // lin1: h3 = relu(h2 @ lin1_w + lin1_b)
  {
    dim3 g(1, (NN+63)/64);
    bgemm64_k<<<g, 256, 0, stream>>>(bufS, 512, lin1T, 512, lin1b, h3, NN, 128);
  }

  // GraphConv residual layers (fused gather + dual GEMM + residual + relu)
  gconv_k<<<(NN+63)/64, 256, 0, stream>>>(h3, l2rT, l2nT, l2b, off, csrc, h4, NN);
  gconv_k<<<(NN+63)/64, 256, 0, stream>>>(h4, l3rT, l3nT, l3b, off, csrc, h5, NN);

  // pool + frame mean + classify
  {
    dim3 g1(16, 13);
    fc1_k<<<g1, 256, 0, stream>>>(h5, partial);
    fc2_k<<<16, 128, 0, stream>>>(partial, fcw, fcb, out);
  }
}